// Round 10
// baseline (1242.184 us; speedup 1.0000x reference)
//
#include <hip/hip_runtime.h>
#include <hip/hip_bf16.h>
#include <stdint.h>

#define BATCH   8
#define NPTS    4096
#define DCH     64
#define NPOINT  1024
#define NSAMPLE 32
#define NEWXYZ_FLOATS (BATCH * NPOINT * 3)

typedef float v2f __attribute__((ext_vector_type(2)));

__device__ __forceinline__ float sqdist_rn(float px, float py, float pz,
                                           float cx, float cy, float cz) {
    // Matches numpy order: ((dx*dx + dy*dy) + dz*dz), round-to-nearest each op, NO fma
    float dx = __fsub_rn(px, cx);
    float dy = __fsub_rn(py, cy);
    float dz = __fsub_rn(pz, cz);
    return __fadd_rn(__fadd_rn(__fmul_rn(dx, dx), __fmul_rn(dy, dy)), __fmul_rn(dz, dz));
}

__device__ __forceinline__ unsigned long long ullmax(unsigned long long a, unsigned long long b) {
    return a > b ? a : b;
}

template <int CTRL>
__device__ __forceinline__ unsigned long long dpp_u64(unsigned long long v) {
    int lo = (int)(unsigned)(v & 0xFFFFFFFFull);
    int hi = (int)(unsigned)(v >> 32);
    lo = __builtin_amdgcn_update_dpp(0, lo, CTRL, 0xF, 0xF, true);  // bound_ctrl: OOB -> 0
    hi = __builtin_amdgcn_update_dpp(0, hi, CTRL, 0xF, 0xF, true);
    return ((unsigned long long)(unsigned)hi << 32) | (unsigned)lo;
}

template <int CTRL>
__device__ __forceinline__ float dpp_f32(float v) {
    return __int_as_float(
        __builtin_amdgcn_update_dpp(0, __float_as_int(v), CTRL, 0xF, 0xF, true));
}

// One tuple-reduction step: max by u64 key, coords ride along (same cmp result).
template <int CTRL>
__device__ __forceinline__ void red_step(unsigned long long& key, float& x, float& y, float& z) {
    const unsigned long long ok = dpp_u64<CTRL>(key);
    const float ox = dpp_f32<CTRL>(x);
    const float oy = dpp_f32<CTRL>(y);
    const float oz = dpp_f32<CTRL>(z);
    const bool take = ok > key;
    key = take ? ok : key;
    x   = take ? ox : x;
    y   = take ? oy : y;
    z   = take ? oz : z;
}

// ---------------- prep: transpose weights (permuted cols for L0/L1), fold BN ----------------
// Column permutation col(o) = (o&7)*8 + (o>>3): lane oo's 8 contiguous columns
// [8oo,8oo+8) hold channels o = oo+8j, making the MLP's LDS X-writes conflict-free.
__global__ void prep_kernel(const float* __restrict__ w0, const float* __restrict__ b0,
                            const float* __restrict__ g0, const float* __restrict__ be0,
                            const float* __restrict__ m0, const float* __restrict__ v0,
                            const float* __restrict__ w1, const float* __restrict__ b1,
                            const float* __restrict__ g1, const float* __restrict__ be1,
                            const float* __restrict__ m1, const float* __restrict__ v1,
                            const float* __restrict__ w2, const float* __restrict__ b2,
                            const float* __restrict__ g2, const float* __restrict__ be2,
                            const float* __restrict__ m2, const float* __restrict__ v2,
                            float* __restrict__ wT0, float* __restrict__ wT1,
                            float* __restrict__ wT2, float* __restrict__ st) {
    const int tid  = blockIdx.x * blockDim.x + threadIdx.x;
    const int nthr = gridDim.x * blockDim.x;
    for (int i = tid; i < 64 * 67; i += nthr) {
        int o = i / 67, c = i % 67;
        wT0[c * 64 + (((o & 7) << 3) | (o >> 3))] = w0[i];
    }
    for (int i = tid; i < 64 * 64; i += nthr) {
        int o = i >> 6, c = i & 63;
        wT1[c * 64 + (((o & 7) << 3) | (o >> 3))] = w1[i];
    }
    for (int i = tid; i < 128 * 64; i += nthr) { int o = i >> 6, c = i & 63; wT2[c * 128 + o] = w2[i]; }
    if (tid < 64) {
        const int col = ((tid & 7) << 3) | (tid >> 3);
        float s = g0[tid] / sqrtf(v0[tid] + 1e-5f);
        st[col] = s;
        st[64 + col] = (b0[tid] - m0[tid]) * s + be0[tid];
        s = g1[tid] / sqrtf(v1[tid] + 1e-5f);
        st[128 + col] = s;
        st[192 + col] = (b1[tid] - m1[tid]) * s + be1[tid];
    }
    if (tid < 128) {
        float s = g2[tid] / sqrtf(v2[tid] + 1e-5f);
        st[256 + tid] = s;
        st[384 + tid] = (b2[tid] - m2[tid]) * s + be2[tid];
    }
}

// ---------------- FPS: one block/batch, 256 thr (1 wave/SIMD), tuple-slot reduce ----------------
// Coords ride the reduction; no dependent second LDS read after the barrier and no
// global stores in the loop. 16 pts/lane; one barrier/step; double-buffered slots.
__global__ __launch_bounds__(256, 1) void fps_kernel(const float* __restrict__ xyz,
                                                     float* __restrict__ newxyz) {
    __shared__ __align__(16) unsigned long long skey[2][4];  // per-wave winner keys
    __shared__ float4 scoord[2][4];                          // per-wave winner coords
    __shared__ float4 snew[NPOINT];                          // 16 KB: selected centroids
    const int b    = blockIdx.x;
    const int tid  = threadIdx.x;
    const int lane = tid & 63;
    const int wid  = tid >> 6;
    const float* xb = xyz + (size_t)b * NPTS * 3;

    // 16 points per thread: slot i -> global index j = tid + i*256 (ascending in i)
    v2f px[8], py[8], pz[8];
    float dd[16];
#pragma unroll
    for (int i = 0; i < 16; ++i) {
        const int j = tid + i * 256;
        px[i >> 1][i & 1] = xb[3 * j];
        py[i >> 1][i & 1] = xb[3 * j + 1];
        pz[i >> 1][i & 1] = xb[3 * j + 2];
        dd[i] = 1e10f;
    }

    float cx = xb[0], cy = xb[1], cz = xb[2];
    if (tid == 0) snew[0] = make_float4(cx, cy, cz, 0.f);
    __syncthreads();

    for (int t = 1; t < NPOINT; ++t) {
        // negated centroid: x + (-c) is bit-identical to x - c (IEEE RN)
        const v2f ncx = {-cx, -cx}, ncy = {-cy, -cy}, ncz = {-cz, -cz};
#pragma unroll
        for (int k = 0; k < 8; ++k) {
            v2f dx, dy, dz, qx, qy, qz, s1, s2;
            asm("v_pk_add_f32 %0, %1, %2" : "=v"(dx) : "v"(px[k]), "v"(ncx));
            asm("v_pk_add_f32 %0, %1, %2" : "=v"(dy) : "v"(py[k]), "v"(ncy));
            asm("v_pk_add_f32 %0, %1, %2" : "=v"(dz) : "v"(pz[k]), "v"(ncz));
            asm("v_pk_mul_f32 %0, %1, %1" : "=v"(qx) : "v"(dx));
            asm("v_pk_mul_f32 %0, %1, %1" : "=v"(qy) : "v"(dy));
            asm("v_pk_mul_f32 %0, %1, %1" : "=v"(qz) : "v"(dz));
            asm("v_pk_add_f32 %0, %1, %2" : "=v"(s1) : "v"(qx), "v"(qy));
            asm("v_pk_add_f32 %0, %1, %2" : "=v"(s2) : "v"(s1), "v"(qz));
            dd[2 * k]     = fminf(dd[2 * k],     s2[0]);
            dd[2 * k + 1] = fminf(dd[2 * k + 1], s2[1]);
        }
        // per-lane max over 16 slots
        float m = dd[0];
#pragma unroll
        for (int i = 1; i < 16; ++i) m = fmaxf(m, dd[i]);
        // first slot attaining m (descending scan => smallest slot, i.e. smallest j)
        int is = 15;
#pragma unroll
        for (int i = 14; i >= 0; --i)
            if (dd[i] == m) is = i;
        const unsigned inv = 0xFFFFFFFFu - (unsigned)(tid + (is << 8));
        // coords of the winning slot via 4-level cndmask select tree (no LDS)
        v2f a0 = (is & 8) ? px[4] : px[0], a1 = (is & 8) ? px[5] : px[1],
            a2_ = (is & 8) ? px[6] : px[2], a3 = (is & 8) ? px[7] : px[3];
        v2f b0 = (is & 8) ? py[4] : py[0], b1 = (is & 8) ? py[5] : py[1],
            b2_ = (is & 8) ? py[6] : py[2], b3 = (is & 8) ? py[7] : py[3];
        v2f g0 = (is & 8) ? pz[4] : pz[0], g1 = (is & 8) ? pz[5] : pz[1],
            g2_ = (is & 8) ? pz[6] : pz[2], g3 = (is & 8) ? pz[7] : pz[3];
        a0 = (is & 4) ? a2_ : a0; a1 = (is & 4) ? a3 : a1;
        b0 = (is & 4) ? b2_ : b0; b1 = (is & 4) ? b3 : b1;
        g0 = (is & 4) ? g2_ : g0; g1 = (is & 4) ? g3 : g1;
        a0 = (is & 2) ? a1 : a0;
        b0 = (is & 2) ? b1 : b0;
        g0 = (is & 2) ? g1 : g0;
        float wx = (is & 1) ? a0[1] : a0[0];
        float wy = (is & 1) ? b0[1] : b0[0];
        float wz = (is & 1) ? g0[1] : g0[0];
        // key: larger dist wins; tie -> larger ~j = smaller index (first-occurrence argmax)
        unsigned long long key =
            ((unsigned long long)__float_as_uint(m) << 32) | (unsigned long long)inv;
        // wave tuple-reduce -> lane 63 holds (key, coords)
        red_step<0x111>(key, wx, wy, wz);  // row_shr:1
        red_step<0x112>(key, wx, wy, wz);  // row_shr:2
        red_step<0x114>(key, wx, wy, wz);  // row_shr:4
        red_step<0x118>(key, wx, wy, wz);  // row_shr:8
        red_step<0x142>(key, wx, wy, wz);  // row_bcast:15
        red_step<0x143>(key, wx, wy, wz);  // row_bcast:31
        if (lane == 63) {
            skey[t & 1][wid]   = key;
            scoord[t & 1][wid] = make_float4(wx, wy, wz, 0.f);
        }
        __syncthreads();

        // combine 4 wave slots: independent broadcast reads, one cndmask tree
        const ulonglong2* kp = (const ulonglong2*)(&skey[t & 1][0]);
        const ulonglong2 ka = kp[0], kb = kp[1];
        const float4 c0 = scoord[t & 1][0], c1 = scoord[t & 1][1];
        const float4 c2 = scoord[t & 1][2], c3 = scoord[t & 1][3];
        const bool t01 = ka.y > ka.x, t23 = kb.y > kb.x;
        const unsigned long long k01 = t01 ? ka.y : ka.x;
        const unsigned long long k23 = t23 ? kb.y : kb.x;
        const float4 c01 = t01 ? c1 : c0;
        const float4 c23 = t23 ? c3 : c2;
        const bool tw = k23 > k01;
        const float4 cw = tw ? c23 : c01;
        cx = cw.x; cy = cw.y; cz = cw.z;
        if (tid == 0) snew[t] = cw;   // LDS only — no vmem in loop
        // double-buffered slots: no second barrier needed (write epoch t+1 targets
        // the other buffer; reuse of this buffer is two barriers away)
    }
    __syncthreads();

    // coalesced dump: LDS snew (float4) -> global newxyz (packed float3)
    float* ob = newxyz + (size_t)b * NPOINT * 3;
    const float* sn = (const float*)snew;
    for (int k = tid; k < NPOINT * 3; k += 256) {
        const int p = k / 3, c = k - 3 * p;
        ob[k] = sn[4 * p + c];
    }
}

// ---------------- ball query: one wave per query ----------------
__global__ __launch_bounds__(256) void ballq_kernel(const float* __restrict__ xyz,
                                                    const float* __restrict__ newxyz,
                                                    int* __restrict__ gidx) {
    __shared__ int g[4][NSAMPLE];
    const int lane = threadIdx.x & 63;
    const int w    = threadIdx.x >> 6;
    const int q    = blockIdx.x * 4 + w;   // b*1024 + s
    const int b    = q >> 10;
    const float* xb = xyz + (size_t)b * NPTS * 3;
    const float* c  = newxyz + (size_t)q * 3;
    const float cx = c[0], cy = c[1], cz = c[2];
    const float r2 = 0.04f;

    int cnt = 0;
    for (int base = 0; base < NPTS; base += 64) {
        const int j = base + lane;
        const float d = sqdist_rn(xb[j * 3 + 0], xb[j * 3 + 1], xb[j * 3 + 2], cx, cy, cz);
        const bool keep = !(d > r2);
        const unsigned long long m = __ballot(keep);
        if (keep) {
            const int slot = cnt + __popcll(m & ((1ull << lane) - 1ull));
            if (slot < NSAMPLE) g[w][slot] = j;
        }
        cnt += (int)__popcll(m);
        if (cnt >= NSAMPLE) break;
    }
    __syncthreads();
    const int first = g[w][0];   // at least the center point itself is within radius
    if (lane < NSAMPLE) {
        const int v = (lane < cnt) ? g[w][lane] : first;
        gidx[(size_t)q * NSAMPLE + lane] = v;
    }
}

// ---------------- grouped MLP + maxpool: one wave per query ----------------
// Output-channel mapping for layers 0/1: lane oo, acc column j -> channel o = oo + 8j
// (weights/st pre-permuted in prep). LDS X row index always equals channel index.
__global__ __launch_bounds__(256) void mlp_kernel(
    const float* __restrict__ xyz, const float* __restrict__ points,
    const float* __restrict__ newxyz, const int* __restrict__ gidx,
    const float* __restrict__ wT0, const float* __restrict__ wT1,
    const float* __restrict__ wT2, const float* __restrict__ st,
    float* __restrict__ outp) {
    __shared__ float Xs[4][68][36];   // per-wave x, channel-major [c][k]
    const int lane = threadIdx.x & 63;
    const int w    = threadIdx.x >> 6;
    const int q    = blockIdx.x * 4 + w;
    const int b    = q >> 10;
    float (*X)[36] = Xs[w];
    const int* gi = gidx + (size_t)q * NSAMPLE;
    const float* nc = newxyz + (size_t)q * 3;
    const float c0 = nc[0], c1 = nc[1], c2 = nc[2];

    // gather: lane = channel, loop over samples; points row is 256B coalesced
    for (int k = 0; k < NSAMPLE; ++k) {
        const int idx = gi[k];
        X[3 + lane][k] = points[((size_t)b * NPTS + idx) * DCH + lane];
        if (lane < 3) {
            const float cv = (lane == 0) ? c0 : ((lane == 1) ? c1 : c2);
            X[lane][k] = xyz[((size_t)b * NPTS + idx) * 3 + lane] - cv;
        }
    }

    const int kk = lane >> 3;  // 4-sample tile
    const int oo = lane & 7;   // 8-out-channel tile

    // ---- layer 0: 67 -> 64
    float acc[4][8];
#pragma unroll
    for (int i = 0; i < 4; ++i)
#pragma unroll
        for (int j = 0; j < 8; ++j) acc[i][j] = 0.f;

    for (int c = 0; c < 67; ++c) {
        const float4 xv = *reinterpret_cast<const float4*>(&X[c][4 * kk]);
        const float4 wa = *reinterpret_cast<const float4*>(&wT0[c * 64 + 8 * oo]);
        const float4 wb = *reinterpret_cast<const float4*>(&wT0[c * 64 + 8 * oo + 4]);
        const float xr[4] = {xv.x, xv.y, xv.z, xv.w};
        const float wr[8] = {wa.x, wa.y, wa.z, wa.w, wb.x, wb.y, wb.z, wb.w};
#pragma unroll
        for (int i = 0; i < 4; ++i)
#pragma unroll
            for (int j = 0; j < 8; ++j)
                acc[i][j] = fmaf(xr[i], wr[j], acc[i][j]);
    }
    {
        const float4 sa = *reinterpret_cast<const float4*>(&st[8 * oo]);
        const float4 sb = *reinterpret_cast<const float4*>(&st[8 * oo + 4]);
        const float4 ta = *reinterpret_cast<const float4*>(&st[64 + 8 * oo]);
        const float4 tb = *reinterpret_cast<const float4*>(&st[64 + 8 * oo + 4]);
        const float sr[8] = {sa.x, sa.y, sa.z, sa.w, sb.x, sb.y, sb.z, sb.w};
        const float tr[8] = {ta.x, ta.y, ta.z, ta.w, tb.x, tb.y, tb.z, tb.w};
#pragma unroll
        for (int j = 0; j < 8; ++j) {
            float4 v;
            v.x = fmaxf(fmaf(acc[0][j], sr[j], tr[j]), 0.f);
            v.y = fmaxf(fmaf(acc[1][j], sr[j], tr[j]), 0.f);
            v.z = fmaxf(fmaf(acc[2][j], sr[j], tr[j]), 0.f);
            v.w = fmaxf(fmaf(acc[3][j], sr[j], tr[j]), 0.f);
            *reinterpret_cast<float4*>(&X[oo + 8 * j][4 * kk]) = v;  // channel oo+8j, conflict-free
        }
    }

    // ---- layer 1: 64 -> 64
#pragma unroll
    for (int i = 0; i < 4; ++i)
#pragma unroll
        for (int j = 0; j < 8; ++j) acc[i][j] = 0.f;

    for (int c = 0; c < 64; ++c) {
        const float4 xv = *reinterpret_cast<const float4*>(&X[c][4 * kk]);
        const float4 wa = *reinterpret_cast<const float4*>(&wT1[c * 64 + 8 * oo]);
        const float4 wb = *reinterpret_cast<const float4*>(&wT1[c * 64 + 8 * oo + 4]);
        const float xr[4] = {xv.x, xv.y, xv.z, xv.w};
        const float wr[8] = {wa.x, wa.y, wa.z, wa.w, wb.x, wb.y, wb.z, wb.w};
#pragma unroll
        for (int i = 0; i < 4; ++i)
#pragma unroll
            for (int j = 0; j < 8; ++j)
                acc[i][j] = fmaf(xr[i], wr[j], acc[i][j]);
    }
    {
        const float4 sa = *reinterpret_cast<const float4*>(&st[128 + 8 * oo]);
        const float4 sb = *reinterpret_cast<const float4*>(&st[128 + 8 * oo + 4]);
        const float4 ta = *reinterpret_cast<const float4*>(&st[192 + 8 * oo]);
        const float4 tb = *reinterpret_cast<const float4*>(&st[192 + 8 * oo + 4]);
        const float sr[8] = {sa.x, sa.y, sa.z, sa.w, sb.x, sb.y, sb.z, sb.w};
        const float tr[8] = {ta.x, ta.y, ta.z, ta.w, tb.x, tb.y, tb.z, tb.w};
#pragma unroll
        for (int j = 0; j < 8; ++j) {
            float4 v;
            v.x = fmaxf(fmaf(acc[0][j], sr[j], tr[j]), 0.f);
            v.y = fmaxf(fmaf(acc[1][j], sr[j], tr[j]), 0.f);
            v.z = fmaxf(fmaf(acc[2][j], sr[j], tr[j]), 0.f);
            v.w = fmaxf(fmaf(acc[3][j], sr[j], tr[j]), 0.f);
            *reinterpret_cast<float4*>(&X[oo + 8 * j][4 * kk]) = v;  // channel oo+8j
        }
    }

    // ---- layer 2: 64 -> 128, fused maxpool over k (unpermuted channel map 16oo+j)
    float a2[4][16];
#pragma unroll
    for (int i = 0; i < 4; ++i)
#pragma unroll
        for (int j = 0; j < 16; ++j) a2[i][j] = 0.f;

    for (int c = 0; c < 64; ++c) {
        const float4 xv = *reinterpret_cast<const float4*>(&X[c][4 * kk]);
        const float xr[4] = {xv.x, xv.y, xv.z, xv.w};
        float wr[16];
#pragma unroll
        for (int j4 = 0; j4 < 4; ++j4) {
            const float4 wv = *reinterpret_cast<const float4*>(&wT2[c * 128 + 16 * oo + 4 * j4]);
            wr[4 * j4 + 0] = wv.x; wr[4 * j4 + 1] = wv.y;
            wr[4 * j4 + 2] = wv.z; wr[4 * j4 + 3] = wv.w;
        }
#pragma unroll
        for (int i = 0; i < 4; ++i)
#pragma unroll
            for (int j = 0; j < 16; ++j)
                a2[i][j] = fmaf(xr[i], wr[j], a2[i][j]);
    }

    float mx[16];
#pragma unroll
    for (int j = 0; j < 16; ++j) {
        const float sj = st[256 + 16 * oo + j];
        const float tj = st[384 + 16 * oo + j];
        float mm = fmaxf(fmaf(a2[0][j], sj, tj), 0.f);
        mm = fmaxf(mm, fmaxf(fmaf(a2[1][j], sj, tj), 0.f));
        mm = fmaxf(mm, fmaxf(fmaf(a2[2][j], sj, tj), 0.f));
        mm = fmaxf(mm, fmaxf(fmaf(a2[3][j], sj, tj), 0.f));
        mx[j] = mm;
    }
#pragma unroll
    for (int j = 0; j < 16; ++j) {
        mx[j] = fmaxf(mx[j], __shfl_xor(mx[j], 8, 64));
        mx[j] = fmaxf(mx[j], __shfl_xor(mx[j], 16, 64));
        mx[j] = fmaxf(mx[j], __shfl_xor(mx[j], 32, 64));
    }
    if (kk == 0) {
        float* dst = outp + (size_t)q * 128 + 16 * oo;
#pragma unroll
        for (int j4 = 0; j4 < 4; ++j4) {
            float4 v;
            v.x = mx[4 * j4 + 0]; v.y = mx[4 * j4 + 1];
            v.z = mx[4 * j4 + 2]; v.w = mx[4 * j4 + 3];
            *reinterpret_cast<float4*>(&dst[4 * j4]) = v;
        }
    }
}

extern "C" void kernel_launch(void* const* d_in, const int* in_sizes, int n_in,
                              void* d_out, int out_size, void* d_ws, size_t ws_size,
                              hipStream_t stream) {
    const float* xyz    = (const float*)d_in[0];
    const float* points = (const float*)d_in[1];
    const float* w0  = (const float*)d_in[2];
    const float* b0  = (const float*)d_in[3];
    const float* g0  = (const float*)d_in[4];
    const float* be0 = (const float*)d_in[5];
    const float* m0  = (const float*)d_in[6];
    const float* v0  = (const float*)d_in[7];
    const float* w1  = (const float*)d_in[8];
    const float* b1  = (const float*)d_in[9];
    const float* g1  = (const float*)d_in[10];
    const float* be1 = (const float*)d_in[11];
    const float* m1  = (const float*)d_in[12];
    const float* v1  = (const float*)d_in[13];
    const float* w2  = (const float*)d_in[14];
    const float* b2  = (const float*)d_in[15];
    const float* g2  = (const float*)d_in[16];
    const float* be2 = (const float*)d_in[17];
    const float* m2  = (const float*)d_in[18];
    const float* v2  = (const float*)d_in[19];

    float* out = (float*)d_out;
    float* ws  = (float*)d_ws;
    float* wT0 = ws;            // 67*64  = 4288
    float* wT1 = ws + 4288;     // 64*64  = 4096
    float* wT2 = ws + 8384;     // 64*128 = 8192
    float* st  = ws + 16576;    // 512 (s0,t0,s1,t1,s2,t2)
    int*   gidx = (int*)(ws + 17088);  // 8192*32 ints

    prep_kernel<<<dim3(17), dim3(256), 0, stream>>>(w0, b0, g0, be0, m0, v0,
                                                    w1, b1, g1, be1, m1, v1,
                                                    w2, b2, g2, be2, m2, v2,
                                                    wT0, wT1, wT2, st);
    fps_kernel<<<dim3(BATCH), dim3(256), 0, stream>>>(xyz, out);
    ballq_kernel<<<dim3(2048), dim3(256), 0, stream>>>(xyz, out, gidx);
    mlp_kernel<<<dim3(2048), dim3(256), 0, stream>>>(xyz, points, out, gidx,
                                                     wT0, wT1, wT2, st,
                                                     out + NEWXYZ_FLOATS);
}